// Round 1
// baseline (215.847 us; speedup 1.0000x reference)
//
#include <hip/hip_runtime.h>
#include <stdint.h>

typedef __attribute__((ext_vector_type(8))) short bf16x8;
typedef __attribute__((ext_vector_type(4))) float f32x4;

__device__ __forceinline__ unsigned short f2bf(float f){
  union { float f; unsigned u; } c; c.f = f;
  unsigned u = c.u;
  u = u + 0x7FFFu + ((u >> 16) & 1u);   // round-to-nearest-even
  return (unsigned short)(u >> 16);
}

__device__ __forceinline__ bf16x8 cvt8(const float* p){
  const float4 a = ((const float4*)p)[0];
  const float4 b = ((const float4*)p)[1];
  bf16x8 r;
  r[0]=(short)f2bf(a.x); r[1]=(short)f2bf(a.y); r[2]=(short)f2bf(a.z); r[3]=(short)f2bf(a.w);
  r[4]=(short)f2bf(b.x); r[5]=(short)f2bf(b.y); r[6]=(short)f2bf(b.z); r[7]=(short)f2bf(b.w);
  return r;
}

// ---------------- Kernel A: QKV projection ----------------
// Per key i: C[rows,64] = X_i[rows,64] @ W[i]^T, rows = 8192*d_i (contiguous).
// Store to Qb/Kb/Vb bf16 layout [B,S,12,64] (inner index o = h*8+mm).
__global__ __launch_bounds__(256) void qkv_proj(
    const float* __restrict__ xA1, const float* __restrict__ xB2,
    const float* __restrict__ xE1, const float* __restrict__ xE2,
    const float* __restrict__ xE3, const float* __restrict__ xE4,
    const float* __restrict__ xE5,
    const float* __restrict__ Wq, const float* __restrict__ Wk,
    const float* __restrict__ Wv,
    unsigned short* __restrict__ Qb, unsigned short* __restrict__ Kb,
    unsigned short* __restrict__ Vb)
{
  const int dims[7] = {1,1,2,2,2,2,2};
  const int rrb_[7] = {0,1,2,4,6,8,10};
  const int tile = blockIdx.x;           // 0..1535
  int i = 0, t0 = 0;
  for (int k = 0; k < 7; ++k){
    int n = 128 * dims[k];
    if (tile >= t0 + n) t0 += n; else { i = k; break; }
  }
  const int d = dims[i], rrb = rrb_[i];
  const float* xp = (i==0)?xA1:(i==1)?xB2:(i==2)?xE1:(i==3)?xE2:(i==4)?xE3:(i==5)?xE4:xE5;

  const int w    = threadIdx.x >> 6;
  const int lane = threadIdx.x & 63;
  const int lo = lane & 15, hi = lane >> 4;
  const int row0 = (tile - t0) * 64 + w * 16;

  // A fragments: X rows (row = lo), feature chunks 8*hi within 32-wide k chunks
  bf16x8 afr[2];
  {
    const float* rp = xp + (size_t)(row0 + lo) * 64;
    afr[0] = cvt8(rp + 8*hi);
    afr[1] = cvt8(rp + 32 + 8*hi);
  }

  const float scale = 0.10206207261596577f;  // 1/sqrt(96)
  const float* Ws[3] = {Wq, Wk, Wv};
  unsigned short* Ob[3] = {Qb, Kb, Vb};

  #pragma unroll
  for (int wsel = 0; wsel < 3; ++wsel){
    const float* Wb = Ws[wsel] + (size_t)i * 64 * 64;
    #pragma unroll
    for (int ot = 0; ot < 4; ++ot){
      f32x4 acc = {0.f,0.f,0.f,0.f};
      #pragma unroll
      for (int c = 0; c < 2; ++c){
        // B[kk][o] = W[o][kk]; lane holds B[8*hi+j][lo+16*ot]
        bf16x8 bfr = cvt8(Wb + (size_t)(lo + 16*ot) * 64 + 32*c + 8*hi);
        acc = __builtin_amdgcn_mfma_f32_16x16x32_bf16(afr[c], bfr, acc, 0, 0, 0);
      }
      const int o = lo + 16*ot;
      #pragma unroll
      for (int r = 0; r < 4; ++r){
        int R  = row0 + hi*4 + r;                 // D row = (lane>>4)*4+r
        int bs = (d == 2) ? (R >> 1) : R;
        int dx = (d == 2) ? (R & 1)  : 0;
        float v = acc[r];
        if (wsel == 0) v *= scale;
        Ob[wsel][(size_t)(bs*12 + rrb + dx) * 64 + o] = f2bf(v);
      }
    }
  }
}

// ---------------- Kernel B: flash attention ----------------
// grid (16 q-tiles, 64 bh). 4 waves x 16 q-rows. KV tiles of 32.
__global__ __launch_bounds__(256) void attn(
    const unsigned short* __restrict__ Qb,
    const unsigned short* __restrict__ Kb,
    const unsigned short* __restrict__ Vb,
    float* __restrict__ Oc)
{
  __shared__ short Kl[32 * 104];      // K tile [32 kv][96 feat], pad to 104
  __shared__ short Vt[96 * 40];       // V^T tile [96 feat][32 kv], pad to 40
  __shared__ short Pl[4][16 * 40];    // per-wave P [16 q][32 kv], pad to 40

  const int qt = blockIdx.x;
  const int bh = blockIdx.y;
  const int b = bh >> 3, h = bh & 7;
  const int w = threadIdx.x >> 6, lane = threadIdx.x & 63;
  const int lo = lane & 15, hi = lane >> 4;
  const int q0 = qt * 64 + w * 16;

  // Q fragments (already scaled by 1/sqrt(96)): row = lo, chunk c covers feats 32c..32c+31
  bf16x8 qf[3];
  {
    const unsigned short* qp = Qb + (size_t)(b*1024 + q0 + lo) * 12 * 64 + h*8;
    #pragma unroll
    for (int c = 0; c < 3; ++c){
      int rr = 4*c + hi;              // f = rr*8 .. rr*8+7 = 32c + 8*hi ..
      qf[c] = *(const bf16x8*)(qp + rr * 64);
    }
  }

  f32x4 acc[6];
  #pragma unroll
  for (int t = 0; t < 6; ++t) acc[t] = (f32x4){0.f,0.f,0.f,0.f};
  float mrun[4], lrun[4];
  #pragma unroll
  for (int r = 0; r < 4; ++r){ mrun[r] = -1e30f; lrun[r] = 0.f; }

  for (int kv0 = 0; kv0 < 1024; kv0 += 32){
    __syncthreads();
    // cooperative stage: K row-major (padded), V transposed
    for (int idx = threadIdx.x; idx < 384; idx += 256){
      int row = idx / 12, rr = idx % 12;
      const size_t g = ((size_t)(b*1024 + kv0 + row) * 12 + rr) * 64 + h*8;
      uint4 kq = *(const uint4*)(Kb + g);
      *(uint4*)&Kl[row*104 + rr*8] = kq;
      uint4 vq = *(const uint4*)(Vb + g);
      const unsigned short* vs = (const unsigned short*)&vq;
      #pragma unroll
      for (int j = 0; j < 8; ++j) Vt[(rr*8 + j)*40 + row] = vs[j];
    }
    __syncthreads();

    // logits: two 16-col halves, 3 k-chunks each
    f32x4 s[2];
    #pragma unroll
    for (int h2 = 0; h2 < 2; ++h2){
      f32x4 sa = {0.f,0.f,0.f,0.f};
      #pragma unroll
      for (int c = 0; c < 3; ++c){
        bf16x8 kf = *(const bf16x8*)&Kl[(h2*16 + lo)*104 + (4*c + hi)*8];
        sa = __builtin_amdgcn_mfma_f32_16x16x32_bf16(qf[c], kf, sa, 0, 0, 0);
      }
      s[h2] = sa;
    }

    // online softmax; lane holds q-rows hi*4+r, kv col h2*16+lo
    #pragma unroll
    for (int r = 0; r < 4; ++r){
      float tm = fmaxf(s[0][r], s[1][r]);
      #pragma unroll
      for (int msk = 1; msk < 16; msk <<= 1) tm = fmaxf(tm, __shfl_xor(tm, msk));
      float mn = fmaxf(mrun[r], tm);
      float al = __expf(mrun[r] - mn);
      float p0 = __expf(s[0][r] - mn);
      float p1 = __expf(s[1][r] - mn);
      float ps = p0 + p1;
      #pragma unroll
      for (int msk = 1; msk < 16; msk <<= 1) ps += __shfl_xor(ps, msk);
      lrun[r] = lrun[r] * al + ps;
      mrun[r] = mn;
      Pl[w][(hi*4 + r)*40 + lo]      = (short)f2bf(p0);
      Pl[w][(hi*4 + r)*40 + 16 + lo] = (short)f2bf(p1);
      #pragma unroll
      for (int t = 0; t < 6; ++t) acc[t][r] *= al;
    }

    // PV: A = P[16x32] (one frag), B = V^T chunks
    bf16x8 pf = *(const bf16x8*)&Pl[w][lo*40 + hi*8];
    #pragma unroll
    for (int ft = 0; ft < 6; ++ft){
      bf16x8 vf = *(const bf16x8*)&Vt[(ft*16 + lo)*40 + hi*8];
      acc[ft] = __builtin_amdgcn_mfma_f32_16x16x32_bf16(pf, vf, acc[ft], 0, 0, 0);
    }
  }

  // epilogue: divide by l, store O [B,S,12,64] f32 (inner = h*8+mm)
  float rl[4];
  #pragma unroll
  for (int r = 0; r < 4; ++r) rl[r] = 1.f / lrun[r];
  #pragma unroll
  for (int ft = 0; ft < 6; ++ft){
    #pragma unroll
    for (int r = 0; r < 4; ++r){
      int f = ft*16 + lo;
      int rr = f >> 3, mm = f & 7;
      size_t a = ((size_t)(b*1024 + q0 + hi*4 + r) * 12 + rr) * 64 + h*8 + mm;
      Oc[a] = acc[ft][r] * rl[r];
    }
  }
}

// ---------------- Kernel C: output projection ----------------
// out[bs, rr, o] = sum_in Oc[bs, rr, in] * Wo[key(rr)][o][in]
__global__ __launch_bounds__(256) void out_proj(
    const float* __restrict__ Oc,
    const float* __restrict__ Wo,
    float* __restrict__ out)
{
  const int dims[7] = {1,1,2,2,2,2,2};
  const int rrb_[7] = {0,1,2,4,6,8,10};
  const int tile = blockIdx.x;
  int i = 0, t0 = 0;
  for (int k = 0; k < 7; ++k){
    int n = 128 * dims[k];
    if (tile >= t0 + n) t0 += n; else { i = k; break; }
  }
  const int d = dims[i], rrb = rrb_[i];
  const int w = threadIdx.x >> 6, lane = threadIdx.x & 63;
  const int lo = lane & 15, hi = lane >> 4;
  const int row0 = (tile - t0) * 64 + w * 16;

  bf16x8 afr[2];
  {
    int R  = row0 + lo;
    int bs = (d == 2) ? (R >> 1) : R;
    int dx = (d == 2) ? (R & 1)  : 0;
    const float* rp = Oc + (size_t)(bs*12 + rrb + dx) * 64;
    afr[0] = cvt8(rp + 8*hi);
    afr[1] = cvt8(rp + 32 + 8*hi);
  }
  const float* Wb = Wo + (size_t)i * 64 * 64;
  #pragma unroll
  for (int ot = 0; ot < 4; ++ot){
    f32x4 acc = {0.f,0.f,0.f,0.f};
    #pragma unroll
    for (int c = 0; c < 2; ++c){
      bf16x8 bfr = cvt8(Wb + (size_t)(lo + 16*ot) * 64 + 32*c + 8*hi);
      acc = __builtin_amdgcn_mfma_f32_16x16x32_bf16(afr[c], bfr, acc, 0, 0, 0);
    }
    #pragma unroll
    for (int r = 0; r < 4; ++r){
      int R  = row0 + hi*4 + r;
      int bs = (d == 2) ? (R >> 1) : R;
      int dx = (d == 2) ? (R & 1)  : 0;
      out[(size_t)(bs*12 + rrb + dx) * 64 + lo + 16*ot] = acc[r];
    }
  }
}

extern "C" void kernel_launch(void* const* d_in, const int* in_sizes, int n_in,
                              void* d_out, int out_size, void* d_ws, size_t ws_size,
                              hipStream_t stream)
{
  const float* xA1 = (const float*)d_in[0];
  const float* xB2 = (const float*)d_in[1];
  const float* xE1 = (const float*)d_in[2];
  const float* xE2 = (const float*)d_in[3];
  const float* xE3 = (const float*)d_in[4];
  const float* xE4 = (const float*)d_in[5];
  const float* xE5 = (const float*)d_in[6];
  const float* Wq  = (const float*)d_in[7];
  const float* Wk  = (const float*)d_in[8];
  const float* Wv  = (const float*)d_in[9];
  const float* Wo  = (const float*)d_in[10];

  const size_t NE = (size_t)8 * 1024 * 12 * 64;   // 6,291,456
  unsigned short* Qb = (unsigned short*)d_ws;
  unsigned short* Kb = Qb + NE;
  unsigned short* Vb = Kb + NE;
  float*          Ocp = (float*)(Vb + NE);        // 25.2 MB; total ws use ~63 MB

  qkv_proj<<<dim3(1536), dim3(256), 0, stream>>>(xA1,xB2,xE1,xE2,xE3,xE4,xE5,
                                                 Wq,Wk,Wv, Qb,Kb,Vb);
  attn<<<dim3(16,64), dim3(256), 0, stream>>>(Qb,Kb,Vb, Ocp);
  out_proj<<<dim3(1536), dim3(256), 0, stream>>>(Ocp, Wo, (float*)d_out);
}

// Round 2
// 143.529 us; speedup vs baseline: 1.5039x; 1.5039x over previous
//
#include <hip/hip_runtime.h>
#include <stdint.h>

typedef __attribute__((ext_vector_type(8))) short bf16x8;
typedef __attribute__((ext_vector_type(4))) float f32x4;
typedef unsigned short ushort_t;

__device__ __forceinline__ unsigned short f2bf(float f){
  union { float f; unsigned u; } c; c.f = f;
  unsigned u = c.u;
  u = u + 0x7FFFu + ((u >> 16) & 1u);   // round-to-nearest-even
  return (unsigned short)(u >> 16);
}

__device__ __forceinline__ bf16x8 cvt8(const float* p){
  const float4 a = ((const float4*)p)[0];
  const float4 b = ((const float4*)p)[1];
  bf16x8 r;
  r[0]=(short)f2bf(a.x); r[1]=(short)f2bf(a.y); r[2]=(short)f2bf(a.z); r[3]=(short)f2bf(a.w);
  r[4]=(short)f2bf(b.x); r[5]=(short)f2bf(b.y); r[6]=(short)f2bf(b.z); r[7]=(short)f2bf(b.w);
  return r;
}

__device__ __forceinline__ uint32_t pk2bf(float a, float b){
  uint32_t r;
  asm("v_cvt_pk_bf16_f32 %0, %1, %2" : "=v"(r) : "v"(a), "v"(b));
  return r;
}

__device__ __forceinline__ float exp2x(float x){
  float r;
  asm("v_exp_f32 %0, %1" : "=v"(r) : "v"(x));
  return r;
}

// ---------------- Kernel A: QKV projection ----------------
// Per key i: C[rows,64] = X_i[rows,64] @ W[i]^T. Store bf16 [B,S,12,64] (inner o = h*8+mm).
// Q pre-scaled by log2(e)/sqrt(96) so attention can use exp2 directly.
__global__ __launch_bounds__(256) void qkv_proj(
    const float* __restrict__ xA1, const float* __restrict__ xB2,
    const float* __restrict__ xE1, const float* __restrict__ xE2,
    const float* __restrict__ xE3, const float* __restrict__ xE4,
    const float* __restrict__ xE5,
    const float* __restrict__ Wq, const float* __restrict__ Wk,
    const float* __restrict__ Wv,
    ushort_t* __restrict__ Qb, ushort_t* __restrict__ Kb,
    ushort_t* __restrict__ Vb)
{
  const int dims[7] = {1,1,2,2,2,2,2};
  const int rrb_[7] = {0,1,2,4,6,8,10};
  const int tile = blockIdx.x;           // 0..1535
  int i = 0, t0 = 0;
  for (int k = 0; k < 7; ++k){
    int n = 128 * dims[k];
    if (tile >= t0 + n) t0 += n; else { i = k; break; }
  }
  const int d = dims[i], rrb = rrb_[i];
  const float* xp = (i==0)?xA1:(i==1)?xB2:(i==2)?xE1:(i==3)?xE2:(i==4)?xE3:(i==5)?xE4:xE5;

  const int lane = threadIdx.x & 63;
  const int w    = threadIdx.x >> 6;
  const int lo = lane & 15, hi = lane >> 4;
  const int row0 = (tile - t0) * 64 + w * 16;

  bf16x8 afr[2];
  {
    const float* rp = xp + (size_t)(row0 + lo) * 64;
    afr[0] = cvt8(rp + 8*hi);
    afr[1] = cvt8(rp + 32 + 8*hi);
  }

  const float scale = 0.14724743479535623f;  // log2(e)/sqrt(96)
  const float* Ws[3] = {Wq, Wk, Wv};
  ushort_t* Ob[3] = {Qb, Kb, Vb};

  #pragma unroll
  for (int wsel = 0; wsel < 3; ++wsel){
    const float* Wb = Ws[wsel] + (size_t)i * 64 * 64;
    #pragma unroll
    for (int ot = 0; ot < 4; ++ot){
      f32x4 acc = {0.f,0.f,0.f,0.f};
      #pragma unroll
      for (int c = 0; c < 2; ++c){
        bf16x8 bfr = cvt8(Wb + (size_t)(lo + 16*ot) * 64 + 32*c + 8*hi);
        acc = __builtin_amdgcn_mfma_f32_16x16x32_bf16(afr[c], bfr, acc, 0, 0, 0);
      }
      const int o = lo + 16*ot;
      #pragma unroll
      for (int r = 0; r < 4; ++r){
        int R  = row0 + hi*4 + r;
        int bs = (d == 2) ? (R >> 1) : R;
        int dx = (d == 2) ? (R & 1)  : 0;
        float v = acc[r];
        if (wsel == 0) v *= scale;
        Ob[wsel][(size_t)(bs*12 + rrb + dx) * 64 + o] = f2bf(v);
      }
    }
  }
}

// ---------------- Kernel B: flash attention (swapped QK^T, O^T accum) ----------------
// grid 512: bid -> (bh, qt) XCD-swizzled. 4 waves x 32 q-rows (2 qblk). KV tiles of 64.
__global__ __launch_bounds__(256) void attn(
    const ushort_t* __restrict__ Qb,
    const ushort_t* __restrict__ Kb,
    const ushort_t* __restrict__ Vb,
    ushort_t* __restrict__ Oc)
{
  __shared__ short    Kl[64*104];            // K tile [64 kv][96 f], pad 104
  __shared__ short    Vt[96*72];             // V^T [96 f][64 kv + pad], col-swizzled kv^8*(rr&3)
  __shared__ uint32_t Pl[4][2][16*36];       // per-wave P packed words [16 q][32 W], pad 36

  const int bid = blockIdx.x;
  const int xcd = bid & 7, u = bid >> 3;
  const int bh = xcd*8 + (u & 7);
  const int qt = u >> 3;
  const int b = bh >> 3, h = bh & 7;
  const int w = threadIdx.x >> 6, lane = threadIdx.x & 63;
  const int lo = lane & 15, hi = lane >> 4;
  const int q0 = qt*128 + w*32;

  // Q fragments (B-operand): B[k=f][col=q], lane holds Q[q0+g*16+lo][32c+8hi+j]
  bf16x8 qf[2][3];
  #pragma unroll
  for (int g = 0; g < 2; ++g)
    #pragma unroll
    for (int c = 0; c < 3; ++c)
      qf[g][c] = *(const bf16x8*)(Qb + ((size_t)(b*1024 + q0 + g*16 + lo)*12 + (4*c+hi))*64 + h*8);

  f32x4 acc[6][2];
  #pragma unroll
  for (int ft = 0; ft < 6; ++ft){ acc[ft][0] = (f32x4){0,0,0,0}; acc[ft][1] = (f32x4){0,0,0,0}; }
  float mr[2] = {-1e30f, -1e30f}, lr[2] = {0.f, 0.f};

  // staging mapping: tid = skv*4 + ss; unit i: rr = 3*ss+i (3 K + 3 V uint4 per thread)
  const int skv = threadIdx.x >> 2;
  const int ss  = threadIdx.x & 3;
  uint4 pk[3], pv[3];

  // preload + write tile 0
  #pragma unroll
  for (int i = 0; i < 3; ++i){
    int rr = 3*ss + i;
    size_t gb = ((size_t)(b*1024 + skv)*12 + rr)*64 + h*8;
    pk[i] = *(const uint4*)(Kb + gb);
    pv[i] = *(const uint4*)(Vb + gb);
  }
  #pragma unroll
  for (int i = 0; i < 3; ++i){
    int rr = 3*ss + i;
    *(uint4*)&Kl[skv*104 + rr*8] = pk[i];
    const ushort_t* vs = (const ushort_t*)&pv[i];
    int swz = (rr & 3) * 8;
    #pragma unroll
    for (int j = 0; j < 8; ++j) Vt[(rr*8+j)*72 + (skv ^ swz)] = vs[j];
  }
  __syncthreads();

  for (int t = 0; t < 16; ++t){
    // prefetch next tile into regs (in flight during compute)
    if (t < 15){
      int kv0 = (t+1)*64;
      #pragma unroll
      for (int i = 0; i < 3; ++i){
        int rr = 3*ss + i;
        size_t gb = ((size_t)(b*1024 + kv0 + skv)*12 + rr)*64 + h*8;
        pk[i] = *(const uint4*)(Kb + gb);
        pv[i] = *(const uint4*)(Vb + gb);
      }
    }

    // QK^T (swapped): S^T[kv][q], A = K-frag, B = Q-frag
    f32x4 st[2][4];
    #pragma unroll
    for (int kvb = 0; kvb < 4; ++kvb){
      bf16x8 kf[3];
      #pragma unroll
      for (int c = 0; c < 3; ++c)
        kf[c] = *(const bf16x8*)&Kl[(kvb*16 + lo)*104 + (4*c+hi)*8];
      #pragma unroll
      for (int g = 0; g < 2; ++g){
        f32x4 s = {0.f,0.f,0.f,0.f};
        #pragma unroll
        for (int c = 0; c < 3; ++c)
          s = __builtin_amdgcn_mfma_f32_16x16x32_bf16(kf[c], qf[g][c], s, 0, 0, 0);
        st[g][kvb] = s;
      }
    }

    // online softmax, per qblk; lane owns q-row = g*16+lo (16 kv logits in regs)
    #pragma unroll
    for (int g = 0; g < 2; ++g){
      float tm = st[g][0][0];
      #pragma unroll
      for (int kvb = 0; kvb < 4; ++kvb)
        #pragma unroll
        for (int r = 0; r < 4; ++r) tm = fmaxf(tm, st[g][kvb][r]);
      tm = fmaxf(tm, __shfl_xor(tm, 16));
      tm = fmaxf(tm, __shfl_xor(tm, 32));
      // defer-max: skip rescale when growth <= 8 (values bounded by 2^8)
      if (!__all(tm - mr[g] <= 8.f)){
        float mn = fmaxf(mr[g], tm);
        float al = exp2x(mr[g] - mn);
        lr[g] *= al;
        #pragma unroll
        for (int ft = 0; ft < 6; ++ft)
          #pragma unroll
          for (int r = 0; r < 4; ++r) acc[ft][g][r] *= al;
        mr[g] = mn;
      }
      float p[4][4], ps = 0.f;
      #pragma unroll
      for (int kvb = 0; kvb < 4; ++kvb)
        #pragma unroll
        for (int r = 0; r < 4; ++r){ p[kvb][r] = exp2x(st[g][kvb][r] - mr[g]); ps += p[kvb][r]; }
      ps += __shfl_xor(ps, 16);
      ps += __shfl_xor(ps, 32);
      lr[g] += ps;
      // pack P words: W = kvb*8 + 2*hi + c  (kv = kvb*16 + 4*hi + 2c + {0,1})
      #pragma unroll
      for (int kvb = 0; kvb < 4; ++kvb)
        #pragma unroll
        for (int c = 0; c < 2; ++c)
          Pl[w][g][lo*36 + kvb*8 + 2*hi + c] = pk2bf(p[kvb][2*c], p[kvb][2*c+1]);
    }

    // PV: O^T[f][q] += V^T-frag x P^T-frag
    bf16x8 pb[2][2];
    #pragma unroll
    for (int g = 0; g < 2; ++g)
      #pragma unroll
      for (int ch = 0; ch < 2; ++ch)
        pb[g][ch] = *(const bf16x8*)&Pl[w][g][lo*36 + ch*16 + 4*hi];
    #pragma unroll
    for (int ch = 0; ch < 2; ++ch){
      #pragma unroll
      for (int ft = 0; ft < 6; ++ft){
        int f = ft*16 + lo;
        int swz = ((f >> 3) & 3) * 8;
        bf16x8 va = *(const bf16x8*)&Vt[f*72 + ((ch*32 + 8*hi) ^ swz)];
        acc[ft][0] = __builtin_amdgcn_mfma_f32_16x16x32_bf16(va, pb[0][ch], acc[ft][0], 0, 0, 0);
        acc[ft][1] = __builtin_amdgcn_mfma_f32_16x16x32_bf16(va, pb[1][ch], acc[ft][1], 0, 0, 0);
      }
    }

    __syncthreads();
    if (t < 15){
      #pragma unroll
      for (int i = 0; i < 3; ++i){
        int rr = 3*ss + i;
        *(uint4*)&Kl[skv*104 + rr*8] = pk[i];
        const ushort_t* vs = (const ushort_t*)&pv[i];
        int swz = (rr & 3) * 8;
        #pragma unroll
        for (int j = 0; j < 8; ++j) Vt[(rr*8+j)*72 + (skv ^ swz)] = vs[j];
      }
    }
    __syncthreads();
  }

  // epilogue: O^T -> bf16 Oc [B,S,12,64] (inner = h*8+mm)
  #pragma unroll
  for (int g = 0; g < 2; ++g){
    float rl = 1.f / lr[g];
    #pragma unroll
    for (int ft = 0; ft < 6; ++ft){
      uint2 o;
      o.x = pk2bf(acc[ft][g][0]*rl, acc[ft][g][1]*rl);
      o.y = pk2bf(acc[ft][g][2]*rl, acc[ft][g][3]*rl);
      int f0 = ft*16 + 4*hi;
      int rr = f0 >> 3, mm0 = f0 & 7;
      size_t ad = ((size_t)(b*1024 + q0 + g*16 + lo)*12 + rr)*64 + h*8 + mm0;
      *(uint2*)(Oc + ad) = o;
    }
  }
}

// ---------------- Kernel C: output projection ----------------
__global__ __launch_bounds__(256) void out_proj(
    const ushort_t* __restrict__ Oc,
    const float* __restrict__ Wo,
    float* __restrict__ out)
{
  const int dims[7] = {1,1,2,2,2,2,2};
  const int rrb_[7] = {0,1,2,4,6,8,10};
  const int tile = blockIdx.x;
  int i = 0, t0 = 0;
  for (int k = 0; k < 7; ++k){
    int n = 128 * dims[k];
    if (tile >= t0 + n) t0 += n; else { i = k; break; }
  }
  const int d = dims[i], rrb = rrb_[i];
  const int w = threadIdx.x >> 6, lane = threadIdx.x & 63;
  const int lo = lane & 15, hi = lane >> 4;
  const int row0 = (tile - t0) * 64 + w * 16;

  bf16x8 afr[2];
  {
    int R  = row0 + lo;
    int bs = (d == 2) ? (R >> 1) : R;
    int dx = (d == 2) ? (R & 1)  : 0;
    const ushort_t* rp = Oc + (size_t)(bs*12 + rrb + dx) * 64;
    afr[0] = *(const bf16x8*)(rp + 8*hi);
    afr[1] = *(const bf16x8*)(rp + 32 + 8*hi);
  }
  const float* Wb = Wo + (size_t)i * 64 * 64;
  #pragma unroll
  for (int ot = 0; ot < 4; ++ot){
    f32x4 acc = {0.f,0.f,0.f,0.f};
    #pragma unroll
    for (int c = 0; c < 2; ++c){
      bf16x8 bfr = cvt8(Wb + (size_t)(lo + 16*ot) * 64 + 32*c + 8*hi);
      acc = __builtin_amdgcn_mfma_f32_16x16x32_bf16(afr[c], bfr, acc, 0, 0, 0);
    }
    #pragma unroll
    for (int r = 0; r < 4; ++r){
      int R  = row0 + hi*4 + r;
      int bs = (d == 2) ? (R >> 1) : R;
      int dx = (d == 2) ? (R & 1)  : 0;
      out[(size_t)(bs*12 + rrb + dx) * 64 + lo + 16*ot] = acc[r];
    }
  }
}

extern "C" void kernel_launch(void* const* d_in, const int* in_sizes, int n_in,
                              void* d_out, int out_size, void* d_ws, size_t ws_size,
                              hipStream_t stream)
{
  const float* xA1 = (const float*)d_in[0];
  const float* xB2 = (const float*)d_in[1];
  const float* xE1 = (const float*)d_in[2];
  const float* xE2 = (const float*)d_in[3];
  const float* xE3 = (const float*)d_in[4];
  const float* xE4 = (const float*)d_in[5];
  const float* xE5 = (const float*)d_in[6];
  const float* Wq  = (const float*)d_in[7];
  const float* Wk  = (const float*)d_in[8];
  const float* Wv  = (const float*)d_in[9];
  const float* Wo  = (const float*)d_in[10];

  const size_t NE = (size_t)8 * 1024 * 12 * 64;   // 6,291,456
  ushort_t* Qb = (ushort_t*)d_ws;
  ushort_t* Kb = Qb + NE;
  ushort_t* Vb = Kb + NE;
  ushort_t* Oc = Vb + NE;                         // all bf16; ~50 MB total

  qkv_proj<<<dim3(1536), dim3(256), 0, stream>>>(xA1,xB2,xE1,xE2,xE3,xE4,xE5,
                                                 Wq,Wk,Wv, Qb,Kb,Vb);
  attn<<<dim3(512), dim3(256), 0, stream>>>(Qb,Kb,Vb, Oc);
  out_proj<<<dim3(1536), dim3(256), 0, stream>>>(Oc, Wo, (float*)d_out);
}